// Round 2
// baseline (249.902 us; speedup 1.0000x reference)
//
#include <hip/hip_runtime.h>
#include <hip/hip_bf16.h>

#define C_DIM 100000
#define NROW 512
#define DDIM 512
#define BN 64
#define BK 64
#define BSTR 72   // LDS row stride (bf16): 144B = 16B-aligned, bank-step 4 -> ~2-way on b128 reads

typedef __attribute__((ext_vector_type(4))) float f32x4;
typedef __attribute__((ext_vector_type(2))) float f32x2;
typedef __attribute__((ext_vector_type(8))) short bf16x8;
typedef __attribute__((ext_vector_type(4))) float f32acc;

// ---------------- kernel 1: inv row norms of W (norm over C per row d) ----------
__global__ __launch_bounds__(256) void cf_knorm(const float* __restrict__ W,
                                                float* __restrict__ inv_norm) {
    const int d = blockIdx.x;
    const float* row = W + (size_t)d * C_DIM;
    float s = 0.f;
    for (int c4 = threadIdx.x; c4 < C_DIM / 4; c4 += 256) {
        f32x4 v = *(const f32x4*)(row + c4 * 4);
        s += v.x * v.x + v.y * v.y + v.z * v.z + v.w * v.w;
    }
    #pragma unroll
    for (int off = 32; off; off >>= 1) s += __shfl_down(s, off, 64);
    __shared__ float wsum[4];
    if ((threadIdx.x & 63) == 0) wsum[threadIdx.x >> 6] = s;
    __syncthreads();
    if (threadIdx.x == 0) {
        float t = wsum[0] + wsum[1] + wsum[2] + wsum[3];
        inv_norm[d] = 1.0f / sqrtf(t);
    }
}

// ---------------- kernel 2: xs = bf16(x * inv_norm[d]) --------------------------
__global__ __launch_bounds__(256) void cf_kxs(const float* __restrict__ x,
                                              const float* __restrict__ inv_norm,
                                              __hip_bfloat16* __restrict__ xs) {
    int idx = blockIdx.x * 256 + threadIdx.x;   // 0..262143
    int d = idx & (DDIM - 1);
    xs[idx] = __float2bfloat16(x[idx] * inv_norm[d]);
}

// ---------------- kernel 3: target logits, cos_m, final -------------------------
__global__ __launch_bounds__(64) void cf_ktgt(const float* __restrict__ x,
                                              const float* __restrict__ W,
                                              const float* __restrict__ inv_norm,
                                              const int* __restrict__ label,
                                              float* __restrict__ tl,
                                              float* __restrict__ cm,
                                              float* __restrict__ fl) {
    const int i = blockIdx.x;
    const int lane = threadIdx.x;
    const int lab = label[i];
    float s = 0.f;
    for (int d = lane; d < DDIM; d += 64)
        s += x[(size_t)i * DDIM + d] * inv_norm[d] * W[(size_t)d * C_DIM + lab];
    #pragma unroll
    for (int off = 32; off; off >>= 1) s += __shfl_down(s, off, 64);
    if (lane == 0) {
        float t = fminf(fmaxf(s, -1.f), 1.f);
        float sn = sqrtf(fmaxf(1.f - t * t, 0.f));
        float c = t * 0.8775825618903728f - sn * 0.479425538604203f; // cos(th+m)
        tl[i] = t;
        cm[i] = c;
        fl[i] = (t > -0.8775825618903728f) ? c : (t - 0.2397127693021015f);
    }
}

// ---------------- kernel 4: t = 0.01 * mean(target_logit) -----------------------
__global__ __launch_bounds__(512) void cf_kt(const float* __restrict__ tl,
                                             float* __restrict__ tout) {
    float s = tl[threadIdx.x];
    #pragma unroll
    for (int off = 32; off; off >>= 1) s += __shfl_down(s, off, 64);
    __shared__ float w[8];
    if ((threadIdx.x & 63) == 0) w[threadIdx.x >> 6] = s;
    __syncthreads();
    if (threadIdx.x == 0) {
        float tt = 0.f;
        #pragma unroll
        for (int j = 0; j < 8; ++j) tt += w[j];
        tout[0] = 0.01f * (tt / 512.0f);
    }
}

// ---------------- kernel 5: GEMM (bf16 MFMA) + fused epilogue -------------------
// BM=512 (all rows, W read once), BN=64, BK=64. 8 waves, each wave owns all 64
// cols x 64 rows (i in [wv*64, wv*64+64)). Swapped operands: mfma(Wfrag, xsfrag)
// -> D[c][i]; reg index walks consecutive c -> dwordx4 epilogue stores.
// T14 pipeline: LOAD(kt+1)->regs early; compute tile kt; cvt+ds_write late;
// ONE barrier per K-step.
__global__ __launch_bounds__(512, 4) void cf_kgemm(
    const __hip_bfloat16* __restrict__ xs,
    const float* __restrict__ W,
    const int* __restrict__ label,
    const float* __restrict__ cosm,
    const float* __restrict__ finl,
    const float* __restrict__ tp,
    float* __restrict__ out) {
    __shared__ __attribute__((aligned(16))) __hip_bfloat16 Bl[2][BN][BSTR];

    const int tid  = threadIdx.x;
    const int wv   = tid >> 6;       // 0..7 -> i base wv*64
    const int lane = tid & 63;
    const int cb   = blockIdx.x * BN;

    // staging decomposition: thread covers k rows {2k2, 2k2+1} x col quad c4
    const int k2 = tid >> 4;          // 0..31
    const int c4 = (tid & 15) * 4;    // 0..60
    const int gc = cb + c4;
    const bool gok = (gc < C_DIM);    // C_DIM%4==0 -> all-or-nothing per quad

    f32acc acc[4][4];   // [m'=c-tile][n'=i-tile]
    #pragma unroll
    for (int m = 0; m < 4; ++m)
        #pragma unroll
        for (int n = 0; n < 4; ++n)
            acc[m][n] = (f32acc){0.f, 0.f, 0.f, 0.f};

    f32x4 r0, r1;   // staged W rows (k=2k2, 2k2+1), 4 cols each

    auto LOADT = [&](int kt) {
        const int kb = kt * BK;
        if (gok) {
            r0 = *(const f32x4*)(W + (size_t)(kb + 2 * k2)     * C_DIM + gc);
            r1 = *(const f32x4*)(W + (size_t)(kb + 2 * k2 + 1) * C_DIM + gc);
        } else {
            r0 = (f32x4){0.f, 0.f, 0.f, 0.f};
            r1 = (f32x4){0.f, 0.f, 0.f, 0.f};
        }
    };
    auto WRITET = [&](int buf) {
        #pragma unroll
        for (int cc = 0; cc < 4; ++cc) {
            union { __hip_bfloat16 h[2]; unsigned u; } p;
            p.h[0] = __float2bfloat16(r0[cc]);
            p.h[1] = __float2bfloat16(r1[cc]);
            *(unsigned*)&Bl[buf][c4 + cc][2 * k2] = p.u;
        }
    };

    LOADT(0);
    WRITET(0);
    __syncthreads();

    const int il = lane & 15;   // c_local (a-frag) / i_local (b-frag)
    const int hi = lane >> 4;   // 0..3
    const int ib = wv * 64;

    #pragma unroll 2
    for (int kt = 0; kt < DDIM / BK; ++kt) {
        const int cur = kt & 1;
        if (kt < DDIM / BK - 1) LOADT(kt + 1);

        const int kb = kt * BK;
        #pragma unroll
        for (int kk = 0; kk < BK; kk += 32) {
            bf16x8 a[4], b[4];
            #pragma unroll
            for (int m = 0; m < 4; ++m)
                a[m] = *(const bf16x8*)&Bl[cur][m * 16 + il][kk + hi * 8];
            #pragma unroll
            for (int n = 0; n < 4; ++n)
                b[n] = *(const bf16x8*)(xs + (size_t)(ib + n * 16 + il) * DDIM + kb + kk + hi * 8);
            #pragma unroll
            for (int m = 0; m < 4; ++m)
                #pragma unroll
                for (int n = 0; n < 4; ++n)
                    acc[m][n] = __builtin_amdgcn_mfma_f32_16x16x32_bf16(a[m], b[n], acc[m][n], 0, 0, 0);
        }

        if (kt < DDIM / BK - 1) WRITET(cur ^ 1);
        __syncthreads();
    }

    // fused epilogue: D[c][i] -> lane holds i = ib + n*16 + il, c = cb + m*16 + hi*4 + r
    const float t = tp[0];
    #pragma unroll
    for (int n = 0; n < 4; ++n) {
        const int i = ib + n * 16 + il;
        const float cmv = cosm[i];
        const float flv = finl[i];
        const int lab = label[i];
        float* orow = out + (size_t)i * C_DIM;
        #pragma unroll
        for (int m = 0; m < 4; ++m) {
            const int c0 = cb + m * 16 + hi * 4;
            if (c0 < C_DIM) {
                f32x4 v = acc[m][n];
                f32x4 o;
                #pragma unroll
                for (int r = 0; r < 4; ++r) {
                    float cz = fminf(fmaxf(v[r], -1.f), 1.f);
                    float ov = (cz > cmv) ? cz * (t + cz) : cz;
                    if (c0 + r == lab) ov = flv;
                    o[r] = ov * 64.0f;
                }
                *(f32x4*)(orow + c0) = o;
            }
        }
    }
}

extern "C" void kernel_launch(void* const* d_in, const int* in_sizes, int n_in,
                              void* d_out, int out_size, void* d_ws, size_t ws_size,
                              hipStream_t stream) {
    const float* x   = (const float*)d_in[0];
    const float* W   = (const float*)d_in[1];
    const int* label = (const int*)d_in[2];
    float* out = (float*)d_out;

    char* ws = (char*)d_ws;
    float* inv_norm = (float*)ws;          // 512 f32
    float* tl  = inv_norm + 512;
    float* cm  = tl + 512;
    float* fl  = cm + 512;
    float* tsc = fl + 512;
    __hip_bfloat16* xs = (__hip_bfloat16*)(ws + 16384);  // 512*512 bf16 = 512KB

    cf_knorm<<<DDIM, 256, 0, stream>>>(W, inv_norm);
    cf_kxs<<<(NROW * DDIM) / 256, 256, 0, stream>>>(x, inv_norm, xs);
    cf_ktgt<<<NROW, 64, 0, stream>>>(x, W, inv_norm, label, tl, cm, fl);
    cf_kt<<<1, 512, 0, stream>>>(tl, tsc);

    const int nblk = (C_DIM + BN - 1) / BN;   // 1563
    cf_kgemm<<<nblk, 512, 0, stream>>>(xs, W, label, cm, fl, tsc, out);
}